// Round 7
// baseline (847.855 us; speedup 1.0000x reference)
//
#include <hip/hip_runtime.h>
#include <hip/hip_bf16.h>

#define S_LEN 1024
#define BATCH 2048
#define HID   64
#define NBLK  BATCH           // one wave per batch row
#define NTHR  64

typedef _Float16 half8 __attribute__((ext_vector_type(8)));
typedef float    f32x4 __attribute__((ext_vector_type(4)));

#define L2E 1.4426950408889634f

// launch_bounds(64, 2): 2 waves/EU -> 256-VGPR budget; the stationary W_hh
// fragments need ~128 VGPRs and MUST NOT be rematerialized (round-5 lesson).
__global__ __launch_bounds__(NTHR, 2) void lstm_kernel(
    const float* __restrict__ x,      // (S, BATCH)
    const float* __restrict__ W_ih,   // (256,1)
    const float* __restrict__ W_hh,   // (256,64)
    const float* __restrict__ b_ih,   // (256,)
    const float* __restrict__ b_hh,   // (256,)
    const float* __restrict__ fc1_w,  // (128,64)
    const float* __restrict__ fc1_b,  // (128,)
    const float* __restrict__ fc2_w,  // (5,128)
    const float* __restrict__ fc2_b,  // (5,)
    float* __restrict__ out)          // (BATCH,5)
{
    // Wave-private state. NO __syncthreads in the whole kernel:
    // same-wave ds_write -> ds_read is ordered via lgkmcnt (wave-synchronous).
    __shared__ __align__(16) _Float16 h_lds[64];   // this batch's h, fp16
    __shared__ __align__(16) float    cbuf[64];    // head: c
    __shared__ __align__(16) float    fbuf[128];   // head: fc1 out

    const int lane = threadIdx.x;     // 0..63
    const int l15  = lane & 15;
    const int quad = lane >> 4;       // 0..3
    const int b    = blockIdx.x;      // batch row
    const int u    = lane;            // unit ownership u = quad*16 + l15 == lane

    // ---- stationary scaled W_hh fragments: tile (g,sub) covers cols
    // g*64 + sub*16 + l15; B-frag lane holds B[k=quad*8+j][n=l15] = W_hh[col][k],
    // k-tile kt adds 32. Pre-scaled by -log2e (sigmoid) / -2log2e (tanh, g).
    // 32 frags = 128 VGPRs, held for the whole loop.
    half8 wf[4][4][2];
    #pragma unroll
    for (int g = 0; g < 4; ++g) {
        const float s = (g == 2) ? (-2.0f * L2E) : (-L2E);
        #pragma unroll
        for (int sub = 0; sub < 4; ++sub) {
            const float* wr = W_hh + (g * 64 + sub * 16 + l15) * HID + quad * 8;
            #pragma unroll
            for (int kt = 0; kt < 2; ++kt) {
                half8 f;
                #pragma unroll
                for (int j = 0; j < 8; ++j) f[j] = (_Float16)(wr[kt * 32 + j] * s);
                wf[g][sub][kt] = f;
            }
        }
    }

    float wih_s[4], bias_s[4];
    #pragma unroll
    for (int g = 0; g < 4; ++g) {
        const int n = g * 64 + u;
        const float s = (g == 2) ? (-2.0f * L2E) : (-L2E);
        wih_s[g]  = W_ih[n] * s;
        bias_s[g] = (b_ih[n] + b_hh[n]) * s;
    }

    // ---- x: wave-uniform column, 4-deep prefetch queue ----
    const float* xcol = x + b;
    float xq[4];
    #pragma unroll
    for (int j = 0; j < 4; ++j) xq[j] = xcol[(size_t)j * BATCH];

    float c = 0.0f;
    h_lds[u] = (_Float16)0.0f;       // h0 = 0 (same-wave ordering suffices)

    const f32x4 zero4 = {0.f, 0.f, 0.f, 0.f};   // loop-invariant C-init regs

    for (int s = 0; s < S_LEN; ++s) {
        const float xv = xq[s & 3];
        {
            int sp = s + 4;
            if (sp > S_LEN - 1) sp = S_LEN - 1;  // clamp; tail values unused
            xq[s & 3] = xcol[(size_t)sp * BATCH];
        }

        // ---- A-frags, fully replicated rows: A[m][k] = h[k] (broadcast reads) ----
        half8 a0 = *(const half8*)(h_lds + quad * 8);        // k 0..31
        half8 a1 = *(const half8*)(h_lds + 32 + quad * 8);   // k 32..63

        // ---- 16 col-tiles, 32 MFMAs; lane keeps tile (g, sub==quad) ----
        float kept[4];
        #pragma unroll
        for (int sub = 0; sub < 4; ++sub) {
            f32x4 acc[4];
            #pragma unroll
            for (int g = 0; g < 4; ++g) {
                f32x4 a = __builtin_amdgcn_mfma_f32_16x16x32_f16(a0, wf[g][sub][0], zero4, 0, 0, 0);
                a       = __builtin_amdgcn_mfma_f32_16x16x32_f16(a1, wf[g][sub][1], a,     0, 0, 0);
                acc[g] = a;
            }
            if (sub == 0) {
                #pragma unroll
                for (int g = 0; g < 4; ++g) kept[g] = acc[g][0];
            } else {
                const bool m = (quad == sub);
                #pragma unroll
                for (int g = 0; g < 4; ++g) kept[g] = m ? acc[g][0] : kept[g];
            }
        }

        // ---- elementwise (lane-local, register-resident) ----
        const float gi = kept[0] + __builtin_fmaf(xv, wih_s[0], bias_s[0]);
        const float gf = kept[1] + __builtin_fmaf(xv, wih_s[1], bias_s[1]);
        const float gg = kept[2] + __builtin_fmaf(xv, wih_s[2], bias_s[2]);
        const float go = kept[3] + __builtin_fmaf(xv, wih_s[3], bias_s[3]);

        const float i_ = __builtin_amdgcn_rcpf(1.0f + __builtin_amdgcn_exp2f(gi));
        const float f_ = __builtin_amdgcn_rcpf(1.0f + __builtin_amdgcn_exp2f(gf));
        const float g_ = 2.0f * __builtin_amdgcn_rcpf(1.0f + __builtin_amdgcn_exp2f(gg)) - 1.0f;
        const float o_ = __builtin_amdgcn_rcpf(1.0f + __builtin_amdgcn_exp2f(go));

        c = f_ * c + i_ * g_;
        const float th = 2.0f * __builtin_amdgcn_rcpf(
                             1.0f + __builtin_amdgcn_exp2f((-2.0f * L2E) * c)) - 1.0f;
        const float h = o_ * th;

        h_lds[u] = (_Float16)h;      // next iter's A-reads are lgkm-ordered
    }

    // ---------- fused FC head on final cell state (no activation) ----------
    cbuf[u] = c;
    // fc1: each lane computes j = lane and j = lane+64
    #pragma unroll
    for (int t = 0; t < 2; ++t) {
        const int j = lane + 64 * t;
        const float* wrow = fc1_w + j * HID;
        float acc = fc1_b[j];
        #pragma unroll
        for (int k = 0; k < HID; k += 4)
            acc += cbuf[k] * wrow[k] + cbuf[k+1] * wrow[k+1]
                 + cbuf[k+2] * wrow[k+2] + cbuf[k+3] * wrow[k+3];
        fbuf[j] = acc;
    }
    // fc2: lanes 0..4
    if (lane < 5) {
        const float* wrow = fc2_w + lane * 128;
        float acc = fc2_b[lane];
        #pragma unroll 4
        for (int j = 0; j < 128; ++j) acc += fbuf[j] * wrow[j];
        out[b * 5 + lane] = acc;
    }
}

extern "C" void kernel_launch(void* const* d_in, const int* in_sizes, int n_in,
                              void* d_out, int out_size, void* d_ws, size_t ws_size,
                              hipStream_t stream) {
    const float* x     = (const float*)d_in[0];
    const float* W_ih  = (const float*)d_in[1];
    const float* W_hh  = (const float*)d_in[2];
    const float* b_ih  = (const float*)d_in[3];
    const float* b_hh  = (const float*)d_in[4];
    const float* fc1_w = (const float*)d_in[5];
    const float* fc1_b = (const float*)d_in[6];
    const float* fc2_w = (const float*)d_in[7];
    const float* fc2_b = (const float*)d_in[8];
    float* out = (float*)d_out;

    lstm_kernel<<<NBLK, NTHR, 0, stream>>>(x, W_ih, W_hh, b_ih, b_hh,
                                           fc1_w, fc1_b, fc2_w, fc2_b, out);
}

// Round 8
// 335.042 us; speedup vs baseline: 2.5306x; 2.5306x over previous
//
#include <hip/hip_runtime.h>
#include <hip/hip_bf16.h>

#define S_LEN 1024
#define BATCH 2048
#define HID   64
#define MB    4               // batch rows per block
#define NBLK  (BATCH / MB)    // 512 blocks -> 2 per CU
#define NTHR  (MB * HID)      // 256 threads = 4 waves

typedef _Float16 half8 __attribute__((ext_vector_type(8)));
typedef float    f32x4 __attribute__((ext_vector_type(4)));
typedef float    f32x4a __attribute__((ext_vector_type(4))) __attribute__((aligned(16)));

#define L2E 1.4426950408889634f
#define HSTRIDE 72            // h row stride in halves (144 B)

// launch_bounds(256, 2): 2 waves/EU = 8 waves/CU = 2 blocks/CU (matches grid).
// min-waves arg is LOAD-BEARING: without it the allocator evicts the stationary
// W_hh fragments and rematerializes them per step (round-5: 6x regression).
__global__ __launch_bounds__(NTHR, 2) void lstm_kernel(
    const float* __restrict__ x,      // (S, BATCH)
    const float* __restrict__ W_ih,   // (256,1)
    const float* __restrict__ W_hh,   // (256,64)
    const float* __restrict__ b_ih,   // (256,)
    const float* __restrict__ b_hh,   // (256,)
    const float* __restrict__ fc1_w,  // (128,64)
    const float* __restrict__ fc1_b,  // (128,)
    const float* __restrict__ fc2_w,  // (5,128)
    const float* __restrict__ fc2_b,  // (5,)
    float* __restrict__ out)          // (BATCH,5)
{
    // x slice for this block: [s][b] 4 floats per step -> 16 KB, staged ONCE.
    // Removing global loads from the loop makes __syncthreads' implicit
    // vmcnt(0) drain free (the m97 barrier-drain gotcha).
    __shared__ __align__(16) float    xs[S_LEN * MB];                // 16 KB
    __shared__ __align__(16) _Float16 h_buf[2][MB * HSTRIDE];        // 1152 B
    __shared__ __align__(16) float    head_lds[MB * HID + MB * 128]; // c + fc1

    const int tid  = threadIdx.x;
    const int lane = tid & 63;
    const int wave = tid >> 6;        // 0..3
    const int l15  = lane & 15;
    const int quad = lane >> 4;       // 0..3
    const int b0   = blockIdx.x * MB;

    // ---- stage x: 1024 rows of float4 (x[s][b0..b0+3]), 4 rows/thread ----
    {
        float4* xs4 = (float4*)xs;
        #pragma unroll
        for (int t = 0; t < 4; ++t) {
            const int s = tid + 256 * t;
            xs4[s] = *(const float4*)(x + (size_t)s * BATCH + b0);
        }
    }

    // ---- zero both h buffers (h0 = 0) ----
    {
        unsigned* hz = (unsigned*)&h_buf[0][0];
        for (int i = tid; i < 2 * MB * HSTRIDE / 2; i += NTHR) hz[i] = 0u;
    }

    // ---- stationary W_hh B-fragments, per-wave unit slice (32 VGPRs) ----
    // wave w, gate g: frag col n=l15 <-> W_hh row g*64 + 16w + l15.
    // B-frag (16x16x32 f16): lane holds B[k=quad*8+j][n=l15]; k-tile kt adds 32.
    // Pre-scaled by -log2e (sigmoid) / -2log2e (tanh on g gate).
    half8 wfrag[4][2];
    #pragma unroll
    for (int g = 0; g < 4; ++g) {
        const float s = (g == 2) ? (-2.0f * L2E) : (-L2E);
        const float* wr = W_hh + (g * 64 + 16 * wave + l15) * HID + quad * 8;
        #pragma unroll
        for (int kt = 0; kt < 2; ++kt) {
            half8 f;
            #pragma unroll
            for (int j = 0; j < 8; ++j) f[j] = (_Float16)(wr[kt * 32 + j] * s);
            wfrag[g][kt] = f;
        }
    }

    // ---- elementwise ownership: thread (quad,l15) -> b=quad, u=16*wave+l15 ----
    const int u = 16 * wave + l15;
    float wih_s[4], bias_s[4];
    #pragma unroll
    for (int g = 0; g < 4; ++g) {
        const int n = g * 64 + u;
        const float s = (g == 2) ? (-2.0f * L2E) : (-L2E);
        wih_s[g]  = W_ih[n] * s;
        bias_s[g] = (b_ih[n] + b_hh[n]) * s;
    }

    float c = 0.0f;
    const f32x4 zero4 = {0.f, 0.f, 0.f, 0.f};   // persistent C-operand regs

    // hoisted pointers (no per-step address recompute beyond +16B on xp)
    const _Float16* a0p = &h_buf[0][0] + (l15 >> 2) * HSTRIDE + quad * 8;
    const _Float16* a1p = &h_buf[1][0] + (l15 >> 2) * HSTRIDE + quad * 8;
    _Float16* w0p = &h_buf[0][0] + quad * HSTRIDE + u;
    _Float16* w1p = &h_buf[1][0] + quad * HSTRIDE + u;
    const float* xp = xs + quad;                 // step s value at xp[4*s]

    __syncthreads();   // x staged + h zeroed visible to all waves

    auto body = [&](int s, const _Float16* ar, _Float16* hw) {
        const float xv = xp[4 * s];              // ds broadcast (16 lanes/addr)

        // ---- MFMA with replicated A: A[m][k] = h[m>>2][k] ----
        // C[row=quad*4+r][col=l15] = gates[batch=quad][unit], identical over r.
        half8 a0 = *(const half8*)(ar);          // k 0..31
        half8 a1 = *(const half8*)(ar + 32);     // k 32..63

        f32x4 acc[4];
        #pragma unroll
        for (int g = 0; g < 4; ++g) {
            acc[g] = __builtin_amdgcn_mfma_f32_16x16x32_f16(a0, wfrag[g][0], zero4, 0, 0, 0);
            acc[g] = __builtin_amdgcn_mfma_f32_16x16x32_f16(a1, wfrag[g][1], acc[g], 0, 0, 0);
        }

        // ---- elementwise: gates register-resident in acc[g][0] ----
        const float gi = acc[0][0] + __builtin_fmaf(xv, wih_s[0], bias_s[0]);
        const float gf = acc[1][0] + __builtin_fmaf(xv, wih_s[1], bias_s[1]);
        const float gg = acc[2][0] + __builtin_fmaf(xv, wih_s[2], bias_s[2]);
        const float go = acc[3][0] + __builtin_fmaf(xv, wih_s[3], bias_s[3]);

        const float i_ = __builtin_amdgcn_rcpf(1.0f + __builtin_amdgcn_exp2f(gi));
        const float f_ = __builtin_amdgcn_rcpf(1.0f + __builtin_amdgcn_exp2f(gf));
        const float g_ = 2.0f * __builtin_amdgcn_rcpf(1.0f + __builtin_amdgcn_exp2f(gg)) - 1.0f;
        const float o_ = __builtin_amdgcn_rcpf(1.0f + __builtin_amdgcn_exp2f(go));

        c = f_ * c + i_ * g_;
        const float th = 2.0f * __builtin_amdgcn_rcpf(
                             1.0f + __builtin_amdgcn_exp2f((-2.0f * L2E) * c)) - 1.0f;
        const float h = o_ * th;

        hw[0] = (_Float16)h;
        __syncthreads();   // only lgkm pressure: no vm ops in flight
    };

    for (int s = 0; s < S_LEN; s += 2) {
        body(s,     a0p, w1p);   // read h_buf[0], write h_buf[1]
        body(s + 1, a1p, w0p);   // read h_buf[1], write h_buf[0]
    }

    // ---------- fused FC head on final cell state (no activation) ----------
    float* c_lds  = head_lds;            // MB*64 floats: [b][u]
    float* h1_lds = head_lds + MB * HID; // MB*128 floats: [b][j]
    c_lds[quad * HID + u] = c;
    __syncthreads();

    for (int idx = tid; idx < MB * 128; idx += NTHR) {
        const int b = idx >> 7, j = idx & 127;
        const float* wrow = fc1_w + j * HID;
        const float* crow = c_lds + b * HID;
        float acc = fc1_b[j];
        #pragma unroll
        for (int k = 0; k < HID; k += 4)
            acc += crow[k] * wrow[k] + crow[k+1] * wrow[k+1]
                 + crow[k+2] * wrow[k+2] + crow[k+3] * wrow[k+3];
        h1_lds[idx] = acc;
    }
    __syncthreads();

    if (tid < MB * 5) {
        const int b = tid / 5, q = tid % 5;
        const float* wrow = fc2_w + q * 128;
        const float* hrow = h1_lds + b * 128;
        float acc = fc2_b[q];
        #pragma unroll 4
        for (int j = 0; j < 128; ++j) acc += hrow[j] * wrow[j];
        out[(b0 + b) * 5 + q] = acc;
    }
}

extern "C" void kernel_launch(void* const* d_in, const int* in_sizes, int n_in,
                              void* d_out, int out_size, void* d_ws, size_t ws_size,
                              hipStream_t stream) {
    const float* x     = (const float*)d_in[0];
    const float* W_ih  = (const float*)d_in[1];
    const float* W_hh  = (const float*)d_in[2];
    const float* b_ih  = (const float*)d_in[3];
    const float* b_hh  = (const float*)d_in[4];
    const float* fc1_w = (const float*)d_in[5];
    const float* fc1_b = (const float*)d_in[6];
    const float* fc2_w = (const float*)d_in[7];
    const float* fc2_b = (const float*)d_in[8];
    float* out = (float*)d_out;

    lstm_kernel<<<NBLK, NTHR, 0, stream>>>(x, W_ih, W_hh, b_ih, b_hh,
                                           fc1_w, fc1_b, fc2_w, fc2_b, out);
}